// Round 8
// baseline (368.856 us; speedup 1.0000x reference)
//
#include <hip/hip_runtime.h>
#include <hip/hip_bf16.h>

#define D 64
#define RSHIFT 9             // 512 nodes per dst-bucket
#define BNODES 512
#define MAXB 256             // >= nb = ceil(100000/512) = 196
#define BCAP 10240           // per-bucket edge capacity (mean 8192, sigma ~90)

typedef unsigned short ushort_t;
typedef unsigned int uint_t;

// pack two fp32 -> two bf16 (RNE) in one uint
__device__ inline uint_t pk_bf16(float x, float y) {
    uint_t ux = __float_as_uint(x); ux = ux + 0x7fffu + ((ux >> 16) & 1u);
    uint_t uy = __float_as_uint(y); uy = uy + 0x7fffu + ((uy >> 16) & 1u);
    return (ux >> 16) | (uy & 0xffff0000u);
}
__device__ inline ushort_t rnd_bf16(float x) {
    uint_t u = __float_as_uint(x); u = u + 0x7fffu + ((u >> 16) & 1u);
    return (ushort_t)(u >> 16);
}

// ---------------- stage 1: bucket edges by dst range ----------------
// NO per-edge global atomics (R4 lesson: each device-scope atomic is a ~32B
// memory-side RMW -> 1.6M of them = ~50MB WRITE_SIZE + ~70us).
__global__ __launch_bounds__(256) void k_bucket(const int* __restrict__ src,
                                                const int* __restrict__ dst,
                                                int* __restrict__ bcur,
                                                int2* __restrict__ ebuf,
                                                int E, int nb) {
    __shared__ int lcnt[MAXB];
    __shared__ int lbase[MAXB];
    int t = threadIdx.x;
    lcnt[t] = 0;
    __syncthreads();
    int base = blockIdx.x * 2048 + t * 8;
    int sv[8], dv[8], sl[8];
    if (base + 7 < E) {
        int4 a0 = *(const int4*)(src + base);
        int4 a1 = *(const int4*)(src + base + 4);
        int4 b0 = *(const int4*)(dst + base);
        int4 b1 = *(const int4*)(dst + base + 4);
        sv[0]=a0.x; sv[1]=a0.y; sv[2]=a0.z; sv[3]=a0.w;
        sv[4]=a1.x; sv[5]=a1.y; sv[6]=a1.z; sv[7]=a1.w;
        dv[0]=b0.x; dv[1]=b0.y; dv[2]=b0.z; dv[3]=b0.w;
        dv[4]=b1.x; dv[5]=b1.y; dv[6]=b1.z; dv[7]=b1.w;
    } else {
        #pragma unroll
        for (int j = 0; j < 8; ++j) {
            dv[j] = (base + j < E) ? dst[base + j] : -1;
            sv[j] = (base + j < E) ? src[base + j] : 0;
        }
    }
    #pragma unroll
    for (int j = 0; j < 8; ++j) {
        if (dv[j] >= 0) {
            int b = dv[j] >> RSHIFT;
            sl[j] = atomicAdd(&lcnt[b], 1);   // LDS atomic only
        }
    }
    __syncthreads();
    if (t < nb) { int c = lcnt[t]; if (c) lbase[t] = atomicAdd(&bcur[t], c); }
    __syncthreads();
    #pragma unroll
    for (int j = 0; j < 8; ++j) {
        if (dv[j] >= 0) {
            int b = dv[j] >> RSHIFT;
            int slot = lbase[b] + sl[j];
            if (slot < BCAP) ebuf[(size_t)b * BCAP + slot] = make_int2(sv[j], dv[j]);
        }
    }
}

// ---------------- stage 2: per-bucket CSR build, all atomics in LDS -------
__global__ __launch_bounds__(256) void k_csr(const int2* __restrict__ ebuf,
                                             const int* __restrict__ bcur,
                                             int* __restrict__ rowptr,
                                             int* __restrict__ ssrc,
                                             float* __restrict__ dis,
                                             int N, int nb) {
    __shared__ int lcnt[BNODES];
    __shared__ int lcur[BNODES];
    __shared__ int sums[256];
    __shared__ int red[4];
    int b = blockIdx.x;
    int t = threadIdx.x;
    int n = bcur[b];
    int node0 = b << RSHIFT;
    int pv = (t < b) ? bcur[t] : 0;
    int lane = t & 63, w = t >> 6;
    #pragma unroll
    for (int off = 1; off < 64; off <<= 1) pv += __shfl_xor(pv, off, 64);
    if (lane == 0) red[w] = pv;
    #pragma unroll
    for (int i = t; i < BNODES; i += 256) lcnt[i] = 0;
    __syncthreads();
    int base = red[0] + red[1] + red[2] + red[3];
    const int2* seg = ebuf + (size_t)b * BCAP;
    for (int i = t * 2; i < n; i += 512) {
        if (i + 1 < n) {
            int4 e = *(const int4*)(seg + i);
            atomicAdd(&lcnt[e.y - node0], 1);
            atomicAdd(&lcnt[e.w - node0], 1);
        } else {
            int2 e = seg[i];
            atomicAdd(&lcnt[e.y - node0], 1);
        }
    }
    __syncthreads();
    int idx = t * 2;
    int v0 = lcnt[idx], v1 = lcnt[idx + 1];
    int s = v0 + v1;
    sums[t] = s;
    __syncthreads();
    for (int off = 1; off < 256; off <<= 1) {
        int x = (t >= off) ? sums[t - off] : 0;
        __syncthreads();
        sums[t] += x;
        __syncthreads();
    }
    int run = sums[t] - s;
    int node = node0 + idx;
    lcur[idx] = base + run;
    if (node < N) { rowptr[node] = base + run; dis[node] = rsqrtf((float)(v0 + 1)); }
    run += v0;
    lcur[idx + 1] = base + run;
    if (node + 1 < N) { rowptr[node + 1] = base + run; dis[node + 1] = rsqrtf((float)(v1 + 1)); }
    if (b == nb - 1 && t == 0) rowptr[N] = base + n;
    __syncthreads();
    for (int i = t * 2; i < n; i += 512) {
        if (i + 1 < n) {
            int4 e = *(const int4*)(seg + i);
            int p0 = atomicAdd(&lcur[e.y - node0], 1); ssrc[p0] = e.x;
            int p1 = atomicAdd(&lcur[e.w - node0], 1); ssrc[p1] = e.z;
        } else {
            int2 e = seg[i];
            int p = atomicAdd(&lcur[e.y - node0], 1); ssrc[p] = e.x;
        }
    }
}

// ---------------- GEMM (layer 0 only): G = bf16((A@W)*dis[row]) ----------
// A-loads software-pipelined (R7: 16 serial global-load rounds were the
// suspected latency bound; prefetch k4+1 while computing k4).
__global__ __launch_bounds__(256) void k_gemm(const float* __restrict__ A,
                                              const float* __restrict__ W,
                                              const float* __restrict__ dis,
                                              ushort_t* __restrict__ G, int N) {
    __shared__ float Wl[D * D];
    int t = threadIdx.x;
    {
        const float4* W4 = (const float4*)W;
        float4* Wl4 = (float4*)Wl;
        #pragma unroll
        for (int i = 0; i < 4; ++i) Wl4[t + i * 256] = W4[t + i * 256];
    }
    __syncthreads();
    int lane = t & 63;
    int wv = t >> 6;
    int q = lane & 3;    // col quarter
    int rg = lane >> 2;  // 0..15 row group
    long row0 = (long)blockIdx.x * 128 + wv * 32 + rg * 2;
    float4 acc[2][4];
    #pragma unroll
    for (int r = 0; r < 2; ++r)
        #pragma unroll
        for (int j = 0; j < 4; ++j) acc[r][j] = make_float4(0.f, 0.f, 0.f, 0.f);
    long rcl[2];
    #pragma unroll
    for (int r = 0; r < 2; ++r) {
        long rr = row0 + r;
        rcl[r] = (rr < N) ? rr : (long)(N - 1);
    }
    float4 xr[2], xn[2];
    #pragma unroll
    for (int r = 0; r < 2; ++r) xr[r] = *(const float4*)(A + rcl[r] * D);
    for (int k4 = 0; k4 < 16; ++k4) {
        if (k4 < 15) {
            #pragma unroll
            for (int r = 0; r < 2; ++r)
                xn[r] = *(const float4*)(A + rcl[r] * D + (k4 + 1) * 4);
        }
        #pragma unroll
        for (int kk = 0; kk < 4; ++kk) {
            int k = k4 * 4 + kk;
            float4 wv4[4];
            #pragma unroll
            for (int j = 0; j < 4; ++j)
                wv4[j] = *(const float4*)(Wl + k * D + q * 16 + j * 4);
            #pragma unroll
            for (int r = 0; r < 2; ++r) {
                float xs = (kk == 0) ? xr[r].x : (kk == 1) ? xr[r].y : (kk == 2) ? xr[r].z : xr[r].w;
                #pragma unroll
                for (int j = 0; j < 4; ++j) {
                    acc[r][j].x += xs * wv4[j].x;
                    acc[r][j].y += xs * wv4[j].y;
                    acc[r][j].z += xs * wv4[j].z;
                    acc[r][j].w += xs * wv4[j].w;
                }
            }
        }
        #pragma unroll
        for (int r = 0; r < 2; ++r) xr[r] = xn[r];
    }
    #pragma unroll
    for (int r = 0; r < 2; ++r) {
        long rr = row0 + r;
        if (rr < N) {
            float sc = dis[rr];
            uint4 p0, p1;
            p0.x = pk_bf16(acc[r][0].x * sc, acc[r][0].y * sc);
            p0.y = pk_bf16(acc[r][0].z * sc, acc[r][0].w * sc);
            p0.z = pk_bf16(acc[r][1].x * sc, acc[r][1].y * sc);
            p0.w = pk_bf16(acc[r][1].z * sc, acc[r][1].w * sc);
            p1.x = pk_bf16(acc[r][2].x * sc, acc[r][2].y * sc);
            p1.y = pk_bf16(acc[r][2].z * sc, acc[r][2].w * sc);
            p1.z = pk_bf16(acc[r][3].x * sc, acc[r][3].y * sc);
            p1.w = pk_bf16(acc[r][3].z * sc, acc[r][3].w * sc);
            uint4* dstp = (uint4*)(G + rr * D + q * 16);
            dstp[0] = p0;
            dstp[1] = p1;
        }
    }
}

#define ACCUM(u)                                                           \
    {                                                                      \
        a[0] += __uint_as_float(u.x << 16);                                \
        a[1] += __uint_as_float(u.x & 0xffff0000u);                        \
        a[2] += __uint_as_float(u.y << 16);                                \
        a[3] += __uint_as_float(u.y & 0xffff0000u);                        \
        a[4] += __uint_as_float(u.z << 16);                                \
        a[5] += __uint_as_float(u.z & 0xffff0000u);                        \
        a[6] += __uint_as_float(u.w << 16);                                \
        a[7] += __uint_as_float(u.w & 0xffff0000u);                        \
    }

// ---------------- fused agg + next-layer GEMM --------------------------
// h[node] = di*(sum_e g[src] + g[node]) + bias  (fp32, in regs/LDS only)
// Gout[node] = bf16((h @ W) * di)
// After the full xor-reduce every lane holds the aggregated row for its 8
// columns; sub==0 lanes stage the 64-float row in LDS (intra-wave, no
// barrier), then each lane computes one output column vs W in LDS
// (bank = lane%32 -> 2-way = free) and stores 2B bf16 (128B/wave).
__global__ __launch_bounds__(256) void k_aggemm(const ushort_t* __restrict__ G,
                                                const float* __restrict__ dis,
                                                const int* __restrict__ rowptr,
                                                const int* __restrict__ ssrc,
                                                const float* __restrict__ bias,
                                                const float* __restrict__ W,
                                                ushort_t* __restrict__ Gout,
                                                int N) {
    __shared__ float Wl[D * D];
    __shared__ float hrow[4][D];
    int t = threadIdx.x;
    {
        const float4* W4 = (const float4*)W;
        float4* Wl4 = (float4*)Wl;
        #pragma unroll
        for (int i = 0; i < 4; ++i) Wl4[t + i * 256] = W4[t + i * 256];
    }
    __syncthreads();
    int wv = t >> 6;
    int lane = t & 63;
    int node = blockIdx.x * 4 + wv;
    if (node >= N) return;
    int sub = lane >> 3;
    int c8 = (lane & 7) * 8;
    int beg = rowptr[node], end = rowptr[node + 1];
    float di = dis[node];
    float a[8];
    #pragma unroll
    for (int j = 0; j < 8; ++j) a[j] = 0.f;
    if (sub == 0) {
        uint4 u = *(const uint4*)(G + (size_t)node * D + c8);
        ACCUM(u);
    }
    int e = beg + sub;
    for (; e + 8 < end; e += 16) {
        int s0 = ssrc[e];
        int s1 = ssrc[e + 8];
        uint4 u0 = *(const uint4*)(G + (size_t)s0 * D + c8);
        uint4 u1 = *(const uint4*)(G + (size_t)s1 * D + c8);
        ACCUM(u0);
        ACCUM(u1);
    }
    if (e < end) {
        int s = ssrc[e];
        uint4 u = *(const uint4*)(G + (size_t)s * D + c8);
        ACCUM(u);
    }
    #pragma unroll
    for (int j = 0; j < 8; ++j) {
        a[j] += __shfl_xor(a[j], 8, 64);
        a[j] += __shfl_xor(a[j], 16, 64);
        a[j] += __shfl_xor(a[j], 32, 64);
    }
    if (sub == 0) {  // h = a*di + bias -> LDS
        float4 bv0 = *(const float4*)(bias + c8);
        float4 bv1 = *(const float4*)(bias + c8 + 4);
        float4 h0, h1;
        h0.x = a[0] * di + bv0.x; h0.y = a[1] * di + bv0.y;
        h0.z = a[2] * di + bv0.z; h0.w = a[3] * di + bv0.w;
        h1.x = a[4] * di + bv1.x; h1.y = a[5] * di + bv1.y;
        h1.z = a[6] * di + bv1.z; h1.w = a[7] * di + bv1.w;
        *(float4*)&hrow[wv][c8] = h0;
        *(float4*)&hrow[wv][c8 + 4] = h1;
    }
    __builtin_amdgcn_wave_barrier();  // intra-wave LDS ordering (sched fence)
    // gemm: lane computes output column `lane`
    float acc = 0.f;
    #pragma unroll
    for (int k4 = 0; k4 < 16; ++k4) {
        float4 h4 = *(const float4*)&hrow[wv][k4 * 4];  // broadcast read
        acc += h4.x * Wl[(k4 * 4 + 0) * D + lane];
        acc += h4.y * Wl[(k4 * 4 + 1) * D + lane];
        acc += h4.z * Wl[(k4 * 4 + 2) * D + lane];
        acc += h4.w * Wl[(k4 * 4 + 3) * D + lane];
    }
    Gout[(size_t)node * D + lane] = rnd_bf16(acc * di);
}

// ---------------- final aggregation: out = di*(sum g) + b (fp32) ---------
__global__ __launch_bounds__(256) void k_agg(const ushort_t* __restrict__ G,
                                             const float* __restrict__ dis,
                                             const int* __restrict__ rowptr,
                                             const int* __restrict__ ssrc,
                                             const float* __restrict__ bias,
                                             float* __restrict__ out, int N) {
    int wv = threadIdx.x >> 6;
    int lane = threadIdx.x & 63;
    int node = blockIdx.x * 4 + wv;
    if (node >= N) return;
    int sub = lane >> 3;
    int c8 = (lane & 7) * 8;
    int beg = rowptr[node], end = rowptr[node + 1];
    float di = dis[node];
    float a[8];
    #pragma unroll
    for (int j = 0; j < 8; ++j) a[j] = 0.f;
    if (sub == 0) {
        uint4 u = *(const uint4*)(G + (size_t)node * D + c8);
        ACCUM(u);
    }
    int e = beg + sub;
    for (; e + 8 < end; e += 16) {
        int s0 = ssrc[e];
        int s1 = ssrc[e + 8];
        uint4 u0 = *(const uint4*)(G + (size_t)s0 * D + c8);
        uint4 u1 = *(const uint4*)(G + (size_t)s1 * D + c8);
        ACCUM(u0);
        ACCUM(u1);
    }
    if (e < end) {
        int s = ssrc[e];
        uint4 u = *(const uint4*)(G + (size_t)s * D + c8);
        ACCUM(u);
    }
    #pragma unroll
    for (int j = 0; j < 8; ++j) {
        a[j] += __shfl_xor(a[j], 8, 64);
        a[j] += __shfl_xor(a[j], 16, 64);
        a[j] += __shfl_xor(a[j], 32, 64);
    }
    if (sub == 0) {
        float4 bv0 = *(const float4*)(bias + c8);
        float4 bv1 = *(const float4*)(bias + c8 + 4);
        float4 r0, r1;
        r0.x = a[0] * di + bv0.x; r0.y = a[1] * di + bv0.y;
        r0.z = a[2] * di + bv0.z; r0.w = a[3] * di + bv0.w;
        r1.x = a[4] * di + bv1.x; r1.y = a[5] * di + bv1.y;
        r1.z = a[6] * di + bv1.z; r1.w = a[7] * di + bv1.w;
        float4* op = (float4*)(out + (size_t)node * D + c8);
        op[0] = r0;
        op[1] = r1;
    }
}
#undef ACCUM

// ---------------- launch ----------------

extern "C" void kernel_launch(void* const* d_in, const int* in_sizes, int n_in,
                              void* d_out, int out_size, void* d_ws, size_t ws_size,
                              hipStream_t stream) {
    const float* x  = (const float*)d_in[0];
    const int*   ei = (const int*)d_in[1];
    const float* W0 = (const float*)d_in[2];
    const float* b0 = (const float*)d_in[3];
    const float* W1 = (const float*)d_in[4];
    const float* b1 = (const float*)d_in[5];
    const float* W2 = (const float*)d_in[6];
    const float* b2 = (const float*)d_in[7];
    float* out = (float*)d_out;

    const int N = in_sizes[0] / D;
    const int E = in_sizes[1] / 2;
    const int* e_src = ei;
    const int* e_dst = ei + E;

    // workspace layout
    ushort_t* GA   = (ushort_t*)d_ws;                          // N*D bf16 = 12.8 MB
    ushort_t* GB   = GA + (size_t)N * D;                       // N*D bf16 = 12.8 MB
    float* dis     = (float*)(GB + (size_t)N * D);             // N
    int*   rowptr  = (int*)(dis + N);                          // N+1
    int*   ssrc    = rowptr + (N + 1);                         // E
    int*   bcur    = ssrc + E;                                 // MAXB
    int2*  ebuf    = (int2*)d_ws;   // nb*BCAP int2 = 16.1 MB, aliases GA/GB head
                                    // (dead before k_gemm writes GA)

    const int nb = (N + BNODES - 1) >> RSHIFT;   // 196
    const int gGemm = (N + 127) / 128;           // 782
    const int gAgg = (N + 3) / 4;

    hipMemsetAsync(bcur, 0, MAXB * sizeof(int), stream);
    k_bucket<<<(E + 2047) / 2048, 256, 0, stream>>>(e_src, e_dst, bcur, ebuf, E, nb);
    k_csr<<<nb, 256, 0, stream>>>(ebuf, bcur, rowptr, ssrc, dis, N, nb);

    // layer 0 gemm: x -> GA
    k_gemm<<<gGemm, 256, 0, stream>>>(x, W0, dis, GA, N);
    // fused agg(l0)+gemm(l1): GA -> GB
    k_aggemm<<<gAgg, 256, 0, stream>>>(GA, dis, rowptr, ssrc, b0, W1, GB, N);
    // fused agg(l1)+gemm(l2): GB -> GA
    k_aggemm<<<gAgg, 256, 0, stream>>>(GB, dis, rowptr, ssrc, b1, W2, GA, N);
    // final agg(l2): GA -> out (fp32)
    k_agg<<<gAgg, 256, 0, stream>>>(GA, dis, rowptr, ssrc, b2, out, N);
}

// Round 9
// 331.936 us; speedup vs baseline: 1.1112x; 1.1112x over previous
//
#include <hip/hip_runtime.h>
#include <hip/hip_bf16.h>

#define D 64
#define RSHIFT 9             // 512 nodes per dst-bucket
#define BNODES 512
#define MAXB 256             // >= nb = ceil(100000/512) = 196
#define BCAP 10240           // per-bucket edge capacity (mean 8192, sigma ~90)

typedef unsigned short ushort_t;
typedef unsigned int uint_t;

// pack two fp32 -> two bf16 (RNE) in one uint (x -> low16, y -> high16)
__device__ inline uint_t pk_bf16(float x, float y) {
    uint_t ux = __float_as_uint(x); ux = ux + 0x7fffu + ((ux >> 16) & 1u);
    uint_t uy = __float_as_uint(y); uy = uy + 0x7fffu + ((uy >> 16) & 1u);
    return (ux >> 16) | (uy & 0xffff0000u);
}

// ---------------- stage 1: bucket edges by dst range ----------------
// Packed entry: (src << 9) | (dst & 511). NO per-edge global atomics
// (R4: device-scope atomic = ~32B memory-side RMW; 1.6M of them = ~70us).
__global__ __launch_bounds__(256) void k_bucket(const int* __restrict__ src,
                                                const int* __restrict__ dst,
                                                int* __restrict__ bcur,
                                                int* __restrict__ ebuf,
                                                int E, int nb) {
    __shared__ int lcnt[MAXB];
    __shared__ int lbase[MAXB];
    int t = threadIdx.x;
    lcnt[t] = 0;
    __syncthreads();
    int base = blockIdx.x * 2048 + t * 8;
    int sv[8], dv[8], sl[8];
    if (base + 7 < E) {
        int4 a0 = *(const int4*)(src + base);
        int4 a1 = *(const int4*)(src + base + 4);
        int4 b0 = *(const int4*)(dst + base);
        int4 b1 = *(const int4*)(dst + base + 4);
        sv[0]=a0.x; sv[1]=a0.y; sv[2]=a0.z; sv[3]=a0.w;
        sv[4]=a1.x; sv[5]=a1.y; sv[6]=a1.z; sv[7]=a1.w;
        dv[0]=b0.x; dv[1]=b0.y; dv[2]=b0.z; dv[3]=b0.w;
        dv[4]=b1.x; dv[5]=b1.y; dv[6]=b1.z; dv[7]=b1.w;
    } else {
        #pragma unroll
        for (int j = 0; j < 8; ++j) {
            dv[j] = (base + j < E) ? dst[base + j] : -1;
            sv[j] = (base + j < E) ? src[base + j] : 0;
        }
    }
    #pragma unroll
    for (int j = 0; j < 8; ++j) {
        if (dv[j] >= 0) {
            int b = dv[j] >> RSHIFT;
            sl[j] = atomicAdd(&lcnt[b], 1);   // LDS atomic only
        }
    }
    __syncthreads();
    if (t < nb) { int c = lcnt[t]; if (c) lbase[t] = atomicAdd(&bcur[t], c); }
    __syncthreads();
    #pragma unroll
    for (int j = 0; j < 8; ++j) {
        if (dv[j] >= 0) {
            int b = dv[j] >> RSHIFT;
            int slot = lbase[b] + sl[j];
            if (slot < BCAP)
                ebuf[(size_t)b * BCAP + slot] = (sv[j] << RSHIFT) | (dv[j] & (BNODES - 1));
        }
    }
}

// ---------------- stage 2: per-bucket CSR build, all atomics in LDS -------
__global__ __launch_bounds__(256) void k_csr(const int* __restrict__ ebuf,
                                             const int* __restrict__ bcur,
                                             int* __restrict__ rowptr,
                                             int* __restrict__ ssrc,
                                             float* __restrict__ dis,
                                             int N, int nb) {
    __shared__ int lcnt[BNODES];
    __shared__ int lcur[BNODES];
    __shared__ int sums[256];
    __shared__ int red[4];
    int b = blockIdx.x;
    int t = threadIdx.x;
    int n = bcur[b];
    int node0 = b << RSHIFT;
    int pv = (t < b) ? bcur[t] : 0;
    int lane = t & 63, w = t >> 6;
    #pragma unroll
    for (int off = 1; off < 64; off <<= 1) pv += __shfl_xor(pv, off, 64);
    if (lane == 0) red[w] = pv;
    #pragma unroll
    for (int i = t; i < BNODES; i += 256) lcnt[i] = 0;
    __syncthreads();
    int base = red[0] + red[1] + red[2] + red[3];
    const int* seg = ebuf + (size_t)b * BCAP;
    // phase A: count (packed entry & 511 = local dst)
    for (int i = t * 4; i < n; i += 1024) {
        if (i + 3 < n) {
            int4 e = *(const int4*)(seg + i);
            atomicAdd(&lcnt[e.x & (BNODES - 1)], 1);
            atomicAdd(&lcnt[e.y & (BNODES - 1)], 1);
            atomicAdd(&lcnt[e.z & (BNODES - 1)], 1);
            atomicAdd(&lcnt[e.w & (BNODES - 1)], 1);
        } else {
            for (int j = 0; j < 4 && i + j < n; ++j)
                atomicAdd(&lcnt[seg[i + j] & (BNODES - 1)], 1);
        }
    }
    __syncthreads();
    // phase B: exclusive scan of 512 counts (2/thread), emit rowptr + dis
    int idx = t * 2;
    int v0 = lcnt[idx], v1 = lcnt[idx + 1];
    int s = v0 + v1;
    sums[t] = s;
    __syncthreads();
    for (int off = 1; off < 256; off <<= 1) {
        int x = (t >= off) ? sums[t - off] : 0;
        __syncthreads();
        sums[t] += x;
        __syncthreads();
    }
    int run = sums[t] - s;
    int node = node0 + idx;
    lcur[idx] = base + run;
    if (node < N) { rowptr[node] = base + run; dis[node] = rsqrtf((float)(v0 + 1)); }
    run += v0;
    lcur[idx + 1] = base + run;
    if (node + 1 < N) { rowptr[node + 1] = base + run; dis[node + 1] = rsqrtf((float)(v1 + 1)); }
    if (b == nb - 1 && t == 0) rowptr[N] = base + n;
    __syncthreads();
    // phase C: scatter into this bucket's contiguous ssrc window
    for (int i = t * 4; i < n; i += 1024) {
        if (i + 3 < n) {
            int4 e = *(const int4*)(seg + i);
            int p0 = atomicAdd(&lcur[e.x & (BNODES - 1)], 1); ssrc[p0] = e.x >> RSHIFT;
            int p1 = atomicAdd(&lcur[e.y & (BNODES - 1)], 1); ssrc[p1] = e.y >> RSHIFT;
            int p2 = atomicAdd(&lcur[e.z & (BNODES - 1)], 1); ssrc[p2] = e.z >> RSHIFT;
            int p3 = atomicAdd(&lcur[e.w & (BNODES - 1)], 1); ssrc[p3] = e.w >> RSHIFT;
        } else {
            for (int j = 0; j < 4 && i + j < n; ++j) {
                int e = seg[i + j];
                int p = atomicAdd(&lcur[e & (BNODES - 1)], 1); ssrc[p] = e >> RSHIFT;
            }
        }
    }
}

// ---------------- GEMM layer 0 (fp32 A): G = bf16((A@W)*dis[row]) --------
// Software-pipelined A-loads; 2 rows/thread, 128 rows/block (~3 blocks/CU).
__global__ __launch_bounds__(256) void k_gemm(const float* __restrict__ A,
                                              const float* __restrict__ W,
                                              const float* __restrict__ dis,
                                              ushort_t* __restrict__ G, int N) {
    __shared__ float Wl[D * D];
    int t = threadIdx.x;
    {
        const float4* W4 = (const float4*)W;
        float4* Wl4 = (float4*)Wl;
        #pragma unroll
        for (int i = 0; i < 4; ++i) Wl4[t + i * 256] = W4[t + i * 256];
    }
    __syncthreads();
    int lane = t & 63;
    int wv = t >> 6;
    int q = lane & 3;
    int rg = lane >> 2;
    long row0 = (long)blockIdx.x * 128 + wv * 32 + rg * 2;
    float4 acc[2][4];
    #pragma unroll
    for (int r = 0; r < 2; ++r)
        #pragma unroll
        for (int j = 0; j < 4; ++j) acc[r][j] = make_float4(0.f, 0.f, 0.f, 0.f);
    long rcl[2];
    #pragma unroll
    for (int r = 0; r < 2; ++r) {
        long rr = row0 + r;
        rcl[r] = (rr < N) ? rr : (long)(N - 1);
    }
    float4 xr[2], xn[2];
    #pragma unroll
    for (int r = 0; r < 2; ++r) xr[r] = *(const float4*)(A + rcl[r] * D);
    for (int k4 = 0; k4 < 16; ++k4) {
        if (k4 < 15) {
            #pragma unroll
            for (int r = 0; r < 2; ++r)
                xn[r] = *(const float4*)(A + rcl[r] * D + (k4 + 1) * 4);
        }
        #pragma unroll
        for (int kk = 0; kk < 4; ++kk) {
            int k = k4 * 4 + kk;
            float4 wv4[4];
            #pragma unroll
            for (int j = 0; j < 4; ++j)
                wv4[j] = *(const float4*)(Wl + k * D + q * 16 + j * 4);
            #pragma unroll
            for (int r = 0; r < 2; ++r) {
                float xs = (kk == 0) ? xr[r].x : (kk == 1) ? xr[r].y : (kk == 2) ? xr[r].z : xr[r].w;
                #pragma unroll
                for (int j = 0; j < 4; ++j) {
                    acc[r][j].x += xs * wv4[j].x;
                    acc[r][j].y += xs * wv4[j].y;
                    acc[r][j].z += xs * wv4[j].z;
                    acc[r][j].w += xs * wv4[j].w;
                }
            }
        }
        #pragma unroll
        for (int r = 0; r < 2; ++r) xr[r] = xn[r];
    }
    #pragma unroll
    for (int r = 0; r < 2; ++r) {
        long rr = row0 + r;
        if (rr < N) {
            float sc = dis[rr];
            uint4 p0, p1;
            p0.x = pk_bf16(acc[r][0].x * sc, acc[r][0].y * sc);
            p0.y = pk_bf16(acc[r][0].z * sc, acc[r][0].w * sc);
            p0.z = pk_bf16(acc[r][1].x * sc, acc[r][1].y * sc);
            p0.w = pk_bf16(acc[r][1].z * sc, acc[r][1].w * sc);
            p1.x = pk_bf16(acc[r][2].x * sc, acc[r][2].y * sc);
            p1.y = pk_bf16(acc[r][2].z * sc, acc[r][2].w * sc);
            p1.z = pk_bf16(acc[r][3].x * sc, acc[r][3].y * sc);
            p1.w = pk_bf16(acc[r][3].z * sc, acc[r][3].w * sc);
            uint4* dstp = (uint4*)(G + rr * D + q * 16);
            dstp[0] = p0;
            dstp[1] = p1;
        }
    }
}

// ---------------- GEMM layers 1/2 (bf16 A): G = bf16((A@W)*dis[row]) -----
__global__ __launch_bounds__(256) void k_gemmb(const ushort_t* __restrict__ A,
                                               const float* __restrict__ W,
                                               const float* __restrict__ dis,
                                               ushort_t* __restrict__ G, int N) {
    __shared__ float Wl[D * D];
    int t = threadIdx.x;
    {
        const float4* W4 = (const float4*)W;
        float4* Wl4 = (float4*)Wl;
        #pragma unroll
        for (int i = 0; i < 4; ++i) Wl4[t + i * 256] = W4[t + i * 256];
    }
    __syncthreads();
    int lane = t & 63;
    int wv = t >> 6;
    int q = lane & 3;
    int rg = lane >> 2;
    long row0 = (long)blockIdx.x * 128 + wv * 32 + rg * 2;
    float4 acc[2][4];
    #pragma unroll
    for (int r = 0; r < 2; ++r)
        #pragma unroll
        for (int j = 0; j < 4; ++j) acc[r][j] = make_float4(0.f, 0.f, 0.f, 0.f);
    long rcl[2];
    #pragma unroll
    for (int r = 0; r < 2; ++r) {
        long rr = row0 + r;
        rcl[r] = (rr < N) ? rr : (long)(N - 1);
    }
    uint4 xr[2], xn[2];
    #pragma unroll
    for (int r = 0; r < 2; ++r) xr[r] = *(const uint4*)(A + rcl[r] * D);
    for (int k8 = 0; k8 < 8; ++k8) {
        if (k8 < 7) {
            #pragma unroll
            for (int r = 0; r < 2; ++r)
                xn[r] = *(const uint4*)(A + rcl[r] * D + (k8 + 1) * 8);
        }
        float xf[2][8];
        #pragma unroll
        for (int r = 0; r < 2; ++r) {
            xf[r][0] = __uint_as_float(xr[r].x << 16);
            xf[r][1] = __uint_as_float(xr[r].x & 0xffff0000u);
            xf[r][2] = __uint_as_float(xr[r].y << 16);
            xf[r][3] = __uint_as_float(xr[r].y & 0xffff0000u);
            xf[r][4] = __uint_as_float(xr[r].z << 16);
            xf[r][5] = __uint_as_float(xr[r].z & 0xffff0000u);
            xf[r][6] = __uint_as_float(xr[r].w << 16);
            xf[r][7] = __uint_as_float(xr[r].w & 0xffff0000u);
        }
        #pragma unroll
        for (int kk = 0; kk < 8; ++kk) {
            int k = k8 * 8 + kk;
            float4 wv4[4];
            #pragma unroll
            for (int j = 0; j < 4; ++j)
                wv4[j] = *(const float4*)(Wl + k * D + q * 16 + j * 4);
            #pragma unroll
            for (int r = 0; r < 2; ++r) {
                float xs = xf[r][kk];
                #pragma unroll
                for (int j = 0; j < 4; ++j) {
                    acc[r][j].x += xs * wv4[j].x;
                    acc[r][j].y += xs * wv4[j].y;
                    acc[r][j].z += xs * wv4[j].z;
                    acc[r][j].w += xs * wv4[j].w;
                }
            }
        }
        #pragma unroll
        for (int r = 0; r < 2; ++r) xr[r] = xn[r];
    }
    #pragma unroll
    for (int r = 0; r < 2; ++r) {
        long rr = row0 + r;
        if (rr < N) {
            float sc = dis[rr];
            uint4 p0, p1;
            p0.x = pk_bf16(acc[r][0].x * sc, acc[r][0].y * sc);
            p0.y = pk_bf16(acc[r][0].z * sc, acc[r][0].w * sc);
            p0.z = pk_bf16(acc[r][1].x * sc, acc[r][1].y * sc);
            p0.w = pk_bf16(acc[r][1].z * sc, acc[r][1].w * sc);
            p1.x = pk_bf16(acc[r][2].x * sc, acc[r][2].y * sc);
            p1.y = pk_bf16(acc[r][2].z * sc, acc[r][2].w * sc);
            p1.z = pk_bf16(acc[r][3].x * sc, acc[r][3].y * sc);
            p1.w = pk_bf16(acc[r][3].z * sc, acc[r][3].w * sc);
            uint4* dstp = (uint4*)(G + rr * D + q * 16);
            dstp[0] = p0;
            dstp[1] = p1;
        }
    }
}

#define ACCUM(u)                                                           \
    {                                                                      \
        a[0] += __uint_as_float(u.x << 16);                                \
        a[1] += __uint_as_float(u.x & 0xffff0000u);                        \
        a[2] += __uint_as_float(u.y << 16);                                \
        a[3] += __uint_as_float(u.y & 0xffff0000u);                        \
        a[4] += __uint_as_float(u.z << 16);                                \
        a[5] += __uint_as_float(u.z & 0xffff0000u);                        \
        a[6] += __uint_as_float(u.w << 16);                                \
        a[7] += __uint_as_float(u.w & 0xffff0000u);                        \
    }

#define AGG_BODY                                                           \
    int wv = threadIdx.x >> 6;                                             \
    int lane = threadIdx.x & 63;                                           \
    int node = blockIdx.x * 4 + wv;                                        \
    if (node >= N) return;                                                 \
    int sub = lane >> 3;                                                   \
    int c8 = (lane & 7) * 8;                                               \
    int beg = rowptr[node], end = rowptr[node + 1];                        \
    float di = dis[node];                                                  \
    float a[8];                                                            \
    _Pragma("unroll")                                                      \
    for (int j = 0; j < 8; ++j) a[j] = 0.f;                                \
    if (sub == 0) {                                                        \
        uint4 u = *(const uint4*)(G + (size_t)node * D + c8);              \
        ACCUM(u);                                                          \
    }                                                                      \
    int e = beg + sub;                                                     \
    for (; e + 8 < end; e += 16) {                                         \
        int s0 = ssrc[e];                                                  \
        int s1 = ssrc[e + 8];                                              \
        uint4 u0 = *(const uint4*)(G + (size_t)s0 * D + c8);               \
        uint4 u1 = *(const uint4*)(G + (size_t)s1 * D + c8);               \
        ACCUM(u0);                                                         \
        ACCUM(u1);                                                         \
    }                                                                      \
    if (e < end) {                                                         \
        int s = ssrc[e];                                                   \
        uint4 u = *(const uint4*)(G + (size_t)s * D + c8);                 \
        ACCUM(u);                                                          \
    }                                                                      \
    _Pragma("unroll")                                                      \
    for (int j = 0; j < 8; ++j) {                                          \
        a[j] += __shfl_xor(a[j], 8, 64);                                   \
        a[j] += __shfl_xor(a[j], 16, 64);                                  \
        a[j] += __shfl_xor(a[j], 32, 64);                                  \
    }

// agg layers 0/1: h = di*(sum g) + b, stored bf16 (halves next gemm's reads)
__global__ __launch_bounds__(256) void k_aggb(const ushort_t* __restrict__ G,
                                              const float* __restrict__ dis,
                                              const int* __restrict__ rowptr,
                                              const int* __restrict__ ssrc,
                                              const float* __restrict__ bias,
                                              ushort_t* __restrict__ Hout, int N) {
    AGG_BODY
    if (sub == 0) {
        float4 bv0 = *(const float4*)(bias + c8);
        float4 bv1 = *(const float4*)(bias + c8 + 4);
        uint4 p;
        p.x = pk_bf16(a[0] * di + bv0.x, a[1] * di + bv0.y);
        p.y = pk_bf16(a[2] * di + bv0.z, a[3] * di + bv0.w);
        p.z = pk_bf16(a[4] * di + bv1.x, a[5] * di + bv1.y);
        p.w = pk_bf16(a[6] * di + bv1.z, a[7] * di + bv1.w);
        *(uint4*)(Hout + (size_t)node * D + c8) = p;
    }
}

// final agg: fp32 output
__global__ __launch_bounds__(256) void k_agg(const ushort_t* __restrict__ G,
                                             const float* __restrict__ dis,
                                             const int* __restrict__ rowptr,
                                             const int* __restrict__ ssrc,
                                             const float* __restrict__ bias,
                                             float* __restrict__ out, int N) {
    AGG_BODY
    if (sub == 0) {
        float4 bv0 = *(const float4*)(bias + c8);
        float4 bv1 = *(const float4*)(bias + c8 + 4);
        float4 r0, r1;
        r0.x = a[0] * di + bv0.x; r0.y = a[1] * di + bv0.y;
        r0.z = a[2] * di + bv0.z; r0.w = a[3] * di + bv0.w;
        r1.x = a[4] * di + bv1.x; r1.y = a[5] * di + bv1.y;
        r1.z = a[6] * di + bv1.z; r1.w = a[7] * di + bv1.w;
        float4* op = (float4*)(out + (size_t)node * D + c8);
        op[0] = r0;
        op[1] = r1;
    }
}
#undef AGG_BODY
#undef ACCUM

// ---------------- launch ----------------

extern "C" void kernel_launch(void* const* d_in, const int* in_sizes, int n_in,
                              void* d_out, int out_size, void* d_ws, size_t ws_size,
                              hipStream_t stream) {
    const float* x  = (const float*)d_in[0];
    const int*   ei = (const int*)d_in[1];
    const float* W0 = (const float*)d_in[2];
    const float* b0 = (const float*)d_in[3];
    const float* W1 = (const float*)d_in[4];
    const float* b1 = (const float*)d_in[5];
    const float* W2 = (const float*)d_in[6];
    const float* b2 = (const float*)d_in[7];
    float* out = (float*)d_out;

    const int N = in_sizes[0] / D;
    const int E = in_sizes[1] / 2;
    const int* e_src = ei;
    const int* e_dst = ei + E;

    // workspace layout
    ushort_t* B0   = (ushort_t*)d_ws;                          // N*D bf16 = 12.8 MB
    ushort_t* B1   = B0 + (size_t)N * D;                       // N*D bf16 = 12.8 MB
    float* dis     = (float*)(B1 + (size_t)N * D);             // N
    int*   rowptr  = (int*)(dis + N);                          // N+1
    int*   ssrc    = rowptr + (N + 1);                         // E
    int*   bcur    = ssrc + E;                                 // MAXB
    int*   ebuf    = (int*)d_ws;    // nb*BCAP int = 8 MB, aliases B0/B1 head
                                    // (dead before k_gemm writes B0)

    const int nb = (N + BNODES - 1) >> RSHIFT;   // 196
    const int gGemm = (N + 127) / 128;           // 782
    const int gAgg = (N + 3) / 4;

    hipMemsetAsync(bcur, 0, MAXB * sizeof(int), stream);
    k_bucket<<<(E + 2047) / 2048, 256, 0, stream>>>(e_src, e_dst, bcur, ebuf, E, nb);
    k_csr<<<nb, 256, 0, stream>>>(ebuf, bcur, rowptr, ssrc, dis, N, nb);

    // layer 0: x --gemm--> B0 --agg--> B1 (bf16)
    k_gemm<<<gGemm, 256, 0, stream>>>(x, W0, dis, B0, N);
    k_aggb<<<gAgg, 256, 0, stream>>>(B0, dis, rowptr, ssrc, b0, B1, N);
    // layer 1: B1 --gemm--> B0 --agg--> B1 (bf16)
    k_gemmb<<<gGemm, 256, 0, stream>>>(B1, W1, dis, B0, N);
    k_aggb<<<gAgg, 256, 0, stream>>>(B0, dis, rowptr, ssrc, b1, B1, N);
    // layer 2: B1 --gemm--> B0 --agg--> out (fp32)
    k_gemmb<<<gGemm, 256, 0, stream>>>(B1, W2, dis, B0, N);
    k_agg<<<gAgg, 256, 0, stream>>>(B0, dis, rowptr, ssrc, b2, out, N);
}

// Round 10
// 302.298 us; speedup vs baseline: 1.2202x; 1.0980x over previous
//
#include <hip/hip_runtime.h>
#include <hip/hip_bf16.h>

#define D 64
#define RSHIFT 9             // 512 nodes per dst-bucket
#define BNODES 512
#define MAXB 256             // >= nb = ceil(100000/512) = 196
#define BCAP 10240           // per-bucket edge capacity (mean 8192, sigma ~90)
#define FH 72                // LDS row stride in bf16 elems: 144B = 9*16B aligned,
                             // 4-bank skew per row -> <=2-way conflicts (free, m136)

typedef unsigned short ushort_t;
typedef unsigned int uint_t;
typedef short short8 __attribute__((ext_vector_type(8)));   // 8 bf16 (4 VGPR) MFMA frag
typedef float floatx4 __attribute__((ext_vector_type(4)));  // MFMA C/D frag

// pack two fp32 -> two bf16 (RNE) in one uint (x -> low16, y -> high16)
__device__ inline uint_t pk_bf16(float x, float y) {
    uint_t ux = __float_as_uint(x); ux = ux + 0x7fffu + ((ux >> 16) & 1u);
    uint_t uy = __float_as_uint(y); uy = uy + 0x7fffu + ((uy >> 16) & 1u);
    return (ux >> 16) | (uy & 0xffff0000u);
}
__device__ inline ushort_t rnd_bf16(float x) {
    uint_t u = __float_as_uint(x); u = u + 0x7fffu + ((u >> 16) & 1u);
    return (ushort_t)(u >> 16);
}

// ---------------- stage 1: bucket edges by dst range ----------------
// Packed entry: (src << 9) | (dst & 511). NO per-edge global atomics
// (R4: device-scope atomic = ~32B memory-side RMW; 1.6M of them = ~70us).
__global__ __launch_bounds__(256) void k_bucket(const int* __restrict__ src,
                                                const int* __restrict__ dst,
                                                int* __restrict__ bcur,
                                                int* __restrict__ ebuf,
                                                int E, int nb) {
    __shared__ int lcnt[MAXB];
    __shared__ int lbase[MAXB];
    int t = threadIdx.x;
    lcnt[t] = 0;
    __syncthreads();
    int base = blockIdx.x * 2048 + t * 8;
    int sv[8], dv[8], sl[8];
    if (base + 7 < E) {
        int4 a0 = *(const int4*)(src + base);
        int4 a1 = *(const int4*)(src + base + 4);
        int4 b0 = *(const int4*)(dst + base);
        int4 b1 = *(const int4*)(dst + base + 4);
        sv[0]=a0.x; sv[1]=a0.y; sv[2]=a0.z; sv[3]=a0.w;
        sv[4]=a1.x; sv[5]=a1.y; sv[6]=a1.z; sv[7]=a1.w;
        dv[0]=b0.x; dv[1]=b0.y; dv[2]=b0.z; dv[3]=b0.w;
        dv[4]=b1.x; dv[5]=b1.y; dv[6]=b1.z; dv[7]=b1.w;
    } else {
        #pragma unroll
        for (int j = 0; j < 8; ++j) {
            dv[j] = (base + j < E) ? dst[base + j] : -1;
            sv[j] = (base + j < E) ? src[base + j] : 0;
        }
    }
    #pragma unroll
    for (int j = 0; j < 8; ++j) {
        if (dv[j] >= 0) {
            int b = dv[j] >> RSHIFT;
            sl[j] = atomicAdd(&lcnt[b], 1);   // LDS atomic only
        }
    }
    __syncthreads();
    if (t < nb) { int c = lcnt[t]; if (c) lbase[t] = atomicAdd(&bcur[t], c); }
    __syncthreads();
    #pragma unroll
    for (int j = 0; j < 8; ++j) {
        if (dv[j] >= 0) {
            int b = dv[j] >> RSHIFT;
            int slot = lbase[b] + sl[j];
            if (slot < BCAP)
                ebuf[(size_t)b * BCAP + slot] = (sv[j] << RSHIFT) | (dv[j] & (BNODES - 1));
        }
    }
}

// ---------------- stage 2: per-bucket CSR build, all atomics in LDS -------
__global__ __launch_bounds__(256) void k_csr(const int* __restrict__ ebuf,
                                             const int* __restrict__ bcur,
                                             int* __restrict__ rowptr,
                                             int* __restrict__ ssrc,
                                             float* __restrict__ dis,
                                             int N, int nb) {
    __shared__ int lcnt[BNODES];
    __shared__ int lcur[BNODES];
    __shared__ int sums[256];
    __shared__ int red[4];
    int b = blockIdx.x;
    int t = threadIdx.x;
    int n = bcur[b];
    int node0 = b << RSHIFT;
    int pv = (t < b) ? bcur[t] : 0;
    int lane = t & 63, w = t >> 6;
    #pragma unroll
    for (int off = 1; off < 64; off <<= 1) pv += __shfl_xor(pv, off, 64);
    if (lane == 0) red[w] = pv;
    #pragma unroll
    for (int i = t; i < BNODES; i += 256) lcnt[i] = 0;
    __syncthreads();
    int base = red[0] + red[1] + red[2] + red[3];
    const int* seg = ebuf + (size_t)b * BCAP;
    for (int i = t * 4; i < n; i += 1024) {
        if (i + 3 < n) {
            int4 e = *(const int4*)(seg + i);
            atomicAdd(&lcnt[e.x & (BNODES - 1)], 1);
            atomicAdd(&lcnt[e.y & (BNODES - 1)], 1);
            atomicAdd(&lcnt[e.z & (BNODES - 1)], 1);
            atomicAdd(&lcnt[e.w & (BNODES - 1)], 1);
        } else {
            for (int j = 0; j < 4 && i + j < n; ++j)
                atomicAdd(&lcnt[seg[i + j] & (BNODES - 1)], 1);
        }
    }
    __syncthreads();
    int idx = t * 2;
    int v0 = lcnt[idx], v1 = lcnt[idx + 1];
    int s = v0 + v1;
    sums[t] = s;
    __syncthreads();
    for (int off = 1; off < 256; off <<= 1) {
        int x = (t >= off) ? sums[t - off] : 0;
        __syncthreads();
        sums[t] += x;
        __syncthreads();
    }
    int run = sums[t] - s;
    int node = node0 + idx;
    lcur[idx] = base + run;
    if (node < N) { rowptr[node] = base + run; dis[node] = rsqrtf((float)(v0 + 1)); }
    run += v0;
    lcur[idx + 1] = base + run;
    if (node + 1 < N) { rowptr[node + 1] = base + run; dis[node + 1] = rsqrtf((float)(v1 + 1)); }
    if (b == nb - 1 && t == 0) rowptr[N] = base + n;
    __syncthreads();
    for (int i = t * 4; i < n; i += 1024) {
        if (i + 3 < n) {
            int4 e = *(const int4*)(seg + i);
            int p0 = atomicAdd(&lcur[e.x & (BNODES - 1)], 1); ssrc[p0] = e.x >> RSHIFT;
            int p1 = atomicAdd(&lcur[e.y & (BNODES - 1)], 1); ssrc[p1] = e.y >> RSHIFT;
            int p2 = atomicAdd(&lcur[e.z & (BNODES - 1)], 1); ssrc[p2] = e.z >> RSHIFT;
            int p3 = atomicAdd(&lcur[e.w & (BNODES - 1)], 1); ssrc[p3] = e.w >> RSHIFT;
        } else {
            for (int j = 0; j < 4 && i + j < n; ++j) {
                int e = seg[i + j];
                int p = atomicAdd(&lcur[e & (BNODES - 1)], 1); ssrc[p] = e >> RSHIFT;
            }
        }
    }
}

// ---------------- GEMM layer 0 (fp32 x): G = bf16((x@W)*dis[row]) --------
// VALU fp32 (no fp32 MFMA on CDNA4); software-pipelined A-loads.
__global__ __launch_bounds__(256) void k_gemm(const float* __restrict__ A,
                                              const float* __restrict__ W,
                                              const float* __restrict__ dis,
                                              ushort_t* __restrict__ G, int N) {
    __shared__ float Wl[D * D];
    int t = threadIdx.x;
    {
        const float4* W4 = (const float4*)W;
        float4* Wl4 = (float4*)Wl;
        #pragma unroll
        for (int i = 0; i < 4; ++i) Wl4[t + i * 256] = W4[t + i * 256];
    }
    __syncthreads();
    int lane = t & 63;
    int wv = t >> 6;
    int q = lane & 3;
    int rg = lane >> 2;
    long row0 = (long)blockIdx.x * 128 + wv * 32 + rg * 2;
    float4 acc[2][4];
    #pragma unroll
    for (int r = 0; r < 2; ++r)
        #pragma unroll
        for (int j = 0; j < 4; ++j) acc[r][j] = make_float4(0.f, 0.f, 0.f, 0.f);
    long rcl[2];
    #pragma unroll
    for (int r = 0; r < 2; ++r) {
        long rr = row0 + r;
        rcl[r] = (rr < N) ? rr : (long)(N - 1);
    }
    float4 xr[2], xn[2];
    #pragma unroll
    for (int r = 0; r < 2; ++r) xr[r] = *(const float4*)(A + rcl[r] * D);
    for (int k4 = 0; k4 < 16; ++k4) {
        if (k4 < 15) {
            #pragma unroll
            for (int r = 0; r < 2; ++r)
                xn[r] = *(const float4*)(A + rcl[r] * D + (k4 + 1) * 4);
        }
        #pragma unroll
        for (int kk = 0; kk < 4; ++kk) {
            int k = k4 * 4 + kk;
            float4 wv4[4];
            #pragma unroll
            for (int j = 0; j < 4; ++j)
                wv4[j] = *(const float4*)(Wl + k * D + q * 16 + j * 4);
            #pragma unroll
            for (int r = 0; r < 2; ++r) {
                float xs = (kk == 0) ? xr[r].x : (kk == 1) ? xr[r].y : (kk == 2) ? xr[r].z : xr[r].w;
                #pragma unroll
                for (int j = 0; j < 4; ++j) {
                    acc[r][j].x += xs * wv4[j].x;
                    acc[r][j].y += xs * wv4[j].y;
                    acc[r][j].z += xs * wv4[j].z;
                    acc[r][j].w += xs * wv4[j].w;
                }
            }
        }
        #pragma unroll
        for (int r = 0; r < 2; ++r) xr[r] = xn[r];
    }
    #pragma unroll
    for (int r = 0; r < 2; ++r) {
        long rr = row0 + r;
        if (rr < N) {
            float sc = dis[rr];
            uint4 p0, p1;
            p0.x = pk_bf16(acc[r][0].x * sc, acc[r][0].y * sc);
            p0.y = pk_bf16(acc[r][0].z * sc, acc[r][0].w * sc);
            p0.z = pk_bf16(acc[r][1].x * sc, acc[r][1].y * sc);
            p0.w = pk_bf16(acc[r][1].z * sc, acc[r][1].w * sc);
            p1.x = pk_bf16(acc[r][2].x * sc, acc[r][2].y * sc);
            p1.y = pk_bf16(acc[r][2].z * sc, acc[r][2].w * sc);
            p1.z = pk_bf16(acc[r][3].x * sc, acc[r][3].y * sc);
            p1.w = pk_bf16(acc[r][3].z * sc, acc[r][3].w * sc);
            uint4* dstp = (uint4*)(G + rr * D + q * 16);
            dstp[0] = p0;
            dstp[1] = p1;
        }
    }
}

// gather-accumulate one node's row: a[0..7] = sum over {self, in-edges} of
// bf16 G rows (8 cols per lane, 8 edge slices, xor-reduce). All 64 lanes
// participate; full row valid on sub==0 lanes afterwards.
__device__ __forceinline__ void agg_gather(const ushort_t* __restrict__ G,
                                           const int* __restrict__ ssrc,
                                           int beg, int end, int sub, int c8,
                                           int node, float a[8]) {
    #pragma unroll
    for (int j = 0; j < 8; ++j) a[j] = 0.f;
    #define ACCUM(u)                                                       \
        {                                                                  \
            a[0] += __uint_as_float(u.x << 16);                            \
            a[1] += __uint_as_float(u.x & 0xffff0000u);                    \
            a[2] += __uint_as_float(u.y << 16);                            \
            a[3] += __uint_as_float(u.y & 0xffff0000u);                    \
            a[4] += __uint_as_float(u.z << 16);                            \
            a[5] += __uint_as_float(u.z & 0xffff0000u);                    \
            a[6] += __uint_as_float(u.w << 16);                            \
            a[7] += __uint_as_float(u.w & 0xffff0000u);                    \
        }
    if (sub == 0) {
        uint4 u = *(const uint4*)(G + (size_t)node * D + c8);
        ACCUM(u);
    }
    int e = beg + sub;
    for (; e + 8 < end; e += 16) {  // 2 gathers in flight (latency)
        int s0 = ssrc[e];
        int s1 = ssrc[e + 8];
        uint4 u0 = *(const uint4*)(G + (size_t)s0 * D + c8);
        uint4 u1 = *(const uint4*)(G + (size_t)s1 * D + c8);
        ACCUM(u0);
        ACCUM(u1);
    }
    if (e < end) {
        int s = ssrc[e];
        uint4 u = *(const uint4*)(G + (size_t)s * D + c8);
        ACCUM(u);
    }
    #undef ACCUM
    #pragma unroll
    for (int j = 0; j < 8; ++j) {
        a[j] += __shfl_xor(a[j], 8, 64);
        a[j] += __shfl_xor(a[j], 16, 64);
        a[j] += __shfl_xor(a[j], 32, 64);
    }
}

// ---------------- fused agg + next-layer MFMA gemm -----------------------
// Block = 64 nodes. Phase 1: 4 waves x 16 nodes gather; h = di*sum + bias ->
// bf16 rows in LDS (stride FH=72). Phase 2: wave computes its 16 rows x 64
// cols via 8x mfma_f32_16x16x32_bf16 (A=h LDS, B=W^T bf16 LDS), epilogue
// *dis -> bf16 Gout. R8 lesson: wave-GEMV fusion = 8.8 LDS-cyc/output;
// R9 model: VALU gemm = LDS-bound (256 b128 W-reads/wave); MFMA needs 10.
__global__ __launch_bounds__(256) void k_fagg(const ushort_t* __restrict__ G,
                                              const float* __restrict__ dis,
                                              const int* __restrict__ rowptr,
                                              const int* __restrict__ ssrc,
                                              const float* __restrict__ bias,
                                              const float* __restrict__ W,
                                              ushort_t* __restrict__ Gout,
                                              int N) {
    __shared__ ushort_t hbuf[64 * FH];
    __shared__ ushort_t wt[64 * FH];   // wt[n][k] = bf16(W[k][n])
    int t = threadIdx.x;
    {   // stage W^T as bf16 (one-time, ~16 float4 reads + 16 2B LDS writes/thr)
        const float4* W4 = (const float4*)W;
        for (int i = t; i < 1024; i += 256) {
            float4 w4 = W4[i];
            int k = i >> 4, n0 = (i & 15) * 4;
            wt[(n0 + 0) * FH + k] = rnd_bf16(w4.x);
            wt[(n0 + 1) * FH + k] = rnd_bf16(w4.y);
            wt[(n0 + 2) * FH + k] = rnd_bf16(w4.z);
            wt[(n0 + 3) * FH + k] = rnd_bf16(w4.w);
        }
    }
    int wv = t >> 6, lane = t & 63;
    int sub = lane >> 3, c8 = (lane & 7) * 8;
    int gbase = blockIdx.x * 64;
    float4 bv0 = *(const float4*)(bias + c8);
    float4 bv1 = *(const float4*)(bias + c8 + 4);
    // phase 1: aggregate 16 nodes per wave into LDS h rows
    for (int i = 0; i < 16; ++i) {
        int node = gbase + wv * 16 + i;     // wave-uniform
        if (node < N) {
            int beg = rowptr[node], end = rowptr[node + 1];
            float di = dis[node];
            float a[8];
            agg_gather(G, ssrc, beg, end, sub, c8, node, a);
            if (sub == 0) {
                uint4 p;
                p.x = pk_bf16(a[0] * di + bv0.x, a[1] * di + bv0.y);
                p.y = pk_bf16(a[2] * di + bv0.z, a[3] * di + bv0.w);
                p.z = pk_bf16(a[4] * di + bv1.x, a[5] * di + bv1.y);
                p.w = pk_bf16(a[6] * di + bv1.z, a[7] * di + bv1.w);
                *(uint4*)&hbuf[(wv * 16 + i) * FH + c8] = p;
            }
        }
    }
    __syncthreads();
    // phase 2: MFMA. A-frag: A[m=lane&15][k=quad*8+j]; B-frag: B^T[n=lane&15][k];
    // C/D: col=lane&15, row=quad*4+reg (guide §3, HW-verified m89/m91).
    int m = lane & 15, quad = lane >> 4;
    short8 a0 = *(short8*)&hbuf[(wv * 16 + m) * FH + quad * 8];
    short8 a1 = *(short8*)&hbuf[(wv * 16 + m) * FH + 32 + quad * 8];
    floatx4 acc[4];
    #pragma unroll
    for (int j = 0; j < 4; ++j) {
        short8 b0 = *(short8*)&wt[(j * 16 + m) * FH + quad * 8];
        short8 b1 = *(short8*)&wt[(j * 16 + m) * FH + 32 + quad * 8];
        floatx4 z = {0.f, 0.f, 0.f, 0.f};
        acc[j] = __builtin_amdgcn_mfma_f32_16x16x32_bf16(a0, b0, z, 0, 0, 0);
        acc[j] = __builtin_amdgcn_mfma_f32_16x16x32_bf16(a1, b1, acc[j], 0, 0, 0);
    }
    int rbase = gbase + wv * 16 + quad * 4;
    #pragma unroll
    for (int r = 0; r < 4; ++r) {
        int row = rbase + r;
        if (row < N) {
            float sc = dis[row];
            #pragma unroll
            for (int j = 0; j < 4; ++j)
                Gout[(size_t)row * D + j * 16 + m] = rnd_bf16(acc[j][r] * sc);
        }
    }
}

// ---------------- final aggregation: out = di*(sum g) + b (fp32) ---------
__global__ __launch_bounds__(256) void k_agg(const ushort_t* __restrict__ G,
                                             const float* __restrict__ dis,
                                             const int* __restrict__ rowptr,
                                             const int* __restrict__ ssrc,
                                             const float* __restrict__ bias,
                                             float* __restrict__ out, int N) {
    int wv = threadIdx.x >> 6;
    int lane = threadIdx.x & 63;
    int node = blockIdx.x * 4 + wv;
    if (node >= N) return;
    int sub = lane >> 3;
    int c8 = (lane & 7) * 8;
    int beg = rowptr[node], end = rowptr[node + 1];
    float di = dis[node];
    float a[8];
    agg_gather(G, ssrc, beg, end, sub, c8, node, a);
    if (sub == 0) {
        float4 bv0 = *(const float4*)(bias + c8);
        float4 bv1 = *(const float4*)(bias + c8 + 4);
        float4 r0, r1;
        r0.x = a[0] * di + bv0.x; r0.y = a[1] * di + bv0.y;
        r0.z = a[2] * di + bv0.z; r0.w = a[3] * di + bv0.w;
        r1.x = a[4] * di + bv1.x; r1.y = a[5] * di + bv1.y;
        r1.z = a[6] * di + bv1.z; r1.w = a[7] * di + bv1.w;
        float4* op = (float4*)(out + (size_t)node * D + c8);
        op[0] = r0;
        op[1] = r1;
    }
}

// ---------------- launch ----------------

extern "C" void kernel_launch(void* const* d_in, const int* in_sizes, int n_in,
                              void* d_out, int out_size, void* d_ws, size_t ws_size,
                              hipStream_t stream) {
    const float* x  = (const float*)d_in[0];
    const int*   ei = (const int*)d_in[1];
    const float* W0 = (const float*)d_in[2];
    const float* b0 = (const float*)d_in[3];
    const float* W1 = (const float*)d_in[4];
    const float* b1 = (const float*)d_in[5];
    const float* W2 = (const float*)d_in[6];
    const float* b2 = (const float*)d_in[7];
    float* out = (float*)d_out;

    const int N = in_sizes[0] / D;
    const int E = in_sizes[1] / 2;
    const int* e_src = ei;
    const int* e_dst = ei + E;

    // workspace layout
    ushort_t* B0   = (ushort_t*)d_ws;                          // N*D bf16 = 12.8 MB
    ushort_t* B1   = B0 + (size_t)N * D;                       // N*D bf16 = 12.8 MB
    float* dis     = (float*)(B1 + (size_t)N * D);             // N
    int*   rowptr  = (int*)(dis + N);                          // N+1
    int*   ssrc    = rowptr + (N + 1);                         // E
    int*   bcur    = ssrc + E;                                 // MAXB
    int*   ebuf    = (int*)d_ws;    // nb*BCAP int = 8 MB, aliases B0 head
                                    // (dead before k_gemm writes B0)

    const int nb = (N + BNODES - 1) >> RSHIFT;   // 196
    const int gGemm = (N + 127) / 128;           // 782
    const int gFagg = (N + 63) / 64;             // 1563
    const int gAgg = (N + 3) / 4;

    hipMemsetAsync(bcur, 0, MAXB * sizeof(int), stream);
    k_bucket<<<(E + 2047) / 2048, 256, 0, stream>>>(e_src, e_dst, bcur, ebuf, E, nb);
    k_csr<<<nb, 256, 0, stream>>>(ebuf, bcur, rowptr, ssrc, dis, N, nb);

    // layer 0 gemm: x -> B0
    k_gemm<<<gGemm, 256, 0, stream>>>(x, W0, dis, B0, N);
    // fused agg(l0) + gemm(l1): B0 -> B1
    k_fagg<<<gFagg, 256, 0, stream>>>(B0, dis, rowptr, ssrc, b0, W1, B1, N);
    // fused agg(l1) + gemm(l2): B1 -> B0
    k_fagg<<<gFagg, 256, 0, stream>>>(B1, dis, rowptr, ssrc, b1, W2, B0, N);
    // final agg(l2): B0 -> out (fp32)
    k_agg<<<gAgg, 256, 0, stream>>>(B0, dis, rowptr, ssrc, b2, out, N);
}

// Round 11
// 295.345 us; speedup vs baseline: 1.2489x; 1.0235x over previous
//
#include <hip/hip_runtime.h>
#include <hip/hip_bf16.h>

#define D 64
#define RSHIFT 9             // 512 nodes per dst-bucket
#define BNODES 512
#define MAXB 256             // >= nb = ceil(100000/512) = 196
#define BCAP 10240           // per-bucket edge capacity (mean 8192, sigma ~90)
#define FH 72                // LDS row stride (bf16): 144B, 4-bank skew per row

typedef unsigned short ushort_t;
typedef unsigned int uint_t;
typedef short short8 __attribute__((ext_vector_type(8)));   // 8 bf16 MFMA frag
typedef float floatx4 __attribute__((ext_vector_type(4)));  // MFMA C/D frag

__device__ inline uint_t pk_bf16(float x, float y) {
    uint_t ux = __float_as_uint(x); ux = ux + 0x7fffu + ((ux >> 16) & 1u);
    uint_t uy = __float_as_uint(y); uy = uy + 0x7fffu + ((uy >> 16) & 1u);
    return (ux >> 16) | (uy & 0xffff0000u);
}
__device__ inline ushort_t rnd_bf16(float x) {
    uint_t u = __float_as_uint(x); u = u + 0x7fffu + ((u >> 16) & 1u);
    return (ushort_t)(u >> 16);
}

// ---------------- stage 1: bucket edges by dst range ----------------
// Packed entry: (src << 9) | (dst & 511). NO per-edge global atomics (R4).
__global__ __launch_bounds__(256) void k_bucket(const int* __restrict__ src,
                                                const int* __restrict__ dst,
                                                int* __restrict__ bcur,
                                                int* __restrict__ ebuf,
                                                int E, int nb) {
    __shared__ int lcnt[MAXB];
    __shared__ int lbase[MAXB];
    int t = threadIdx.x;
    lcnt[t] = 0;
    __syncthreads();
    int base = blockIdx.x * 2048 + t * 8;
    int sv[8], dv[8], sl[8];
    if (base + 7 < E) {
        int4 a0 = *(const int4*)(src + base);
        int4 a1 = *(const int4*)(src + base + 4);
        int4 b0 = *(const int4*)(dst + base);
        int4 b1 = *(const int4*)(dst + base + 4);
        sv[0]=a0.x; sv[1]=a0.y; sv[2]=a0.z; sv[3]=a0.w;
        sv[4]=a1.x; sv[5]=a1.y; sv[6]=a1.z; sv[7]=a1.w;
        dv[0]=b0.x; dv[1]=b0.y; dv[2]=b0.z; dv[3]=b0.w;
        dv[4]=b1.x; dv[5]=b1.y; dv[6]=b1.z; dv[7]=b1.w;
    } else {
        #pragma unroll
        for (int j = 0; j < 8; ++j) {
            dv[j] = (base + j < E) ? dst[base + j] : -1;
            sv[j] = (base + j < E) ? src[base + j] : 0;
        }
    }
    #pragma unroll
    for (int j = 0; j < 8; ++j) {
        if (dv[j] >= 0) {
            int b = dv[j] >> RSHIFT;
            sl[j] = atomicAdd(&lcnt[b], 1);   // LDS atomic only
        }
    }
    __syncthreads();
    if (t < nb) { int c = lcnt[t]; if (c) lbase[t] = atomicAdd(&bcur[t], c); }
    __syncthreads();
    #pragma unroll
    for (int j = 0; j < 8; ++j) {
        if (dv[j] >= 0) {
            int b = dv[j] >> RSHIFT;
            int slot = lbase[b] + sl[j];
            if (slot < BCAP)
                ebuf[(size_t)b * BCAP + slot] = (sv[j] << RSHIFT) | (dv[j] & (BNODES - 1));
        }
    }
}

// ---------------- stage 2: per-bucket CSR build, all atomics in LDS -------
__global__ __launch_bounds__(256) void k_csr(const int* __restrict__ ebuf,
                                             const int* __restrict__ bcur,
                                             int* __restrict__ rowptr,
                                             int* __restrict__ ssrc,
                                             float* __restrict__ dis,
                                             int N, int nb) {
    __shared__ int lcnt[BNODES];
    __shared__ int lcur[BNODES];
    __shared__ int sums[256];
    __shared__ int red[4];
    int b = blockIdx.x;
    int t = threadIdx.x;
    int n = bcur[b];
    int node0 = b << RSHIFT;
    int pv = (t < b) ? bcur[t] : 0;
    int lane = t & 63, w = t >> 6;
    #pragma unroll
    for (int off = 1; off < 64; off <<= 1) pv += __shfl_xor(pv, off, 64);
    if (lane == 0) red[w] = pv;
    #pragma unroll
    for (int i = t; i < BNODES; i += 256) lcnt[i] = 0;
    __syncthreads();
    int base = red[0] + red[1] + red[2] + red[3];
    const int* seg = ebuf + (size_t)b * BCAP;
    for (int i = t * 4; i < n; i += 1024) {
        if (i + 3 < n) {
            int4 e = *(const int4*)(seg + i);
            atomicAdd(&lcnt[e.x & (BNODES - 1)], 1);
            atomicAdd(&lcnt[e.y & (BNODES - 1)], 1);
            atomicAdd(&lcnt[e.z & (BNODES - 1)], 1);
            atomicAdd(&lcnt[e.w & (BNODES - 1)], 1);
        } else {
            for (int j = 0; j < 4 && i + j < n; ++j)
                atomicAdd(&lcnt[seg[i + j] & (BNODES - 1)], 1);
        }
    }
    __syncthreads();
    int idx = t * 2;
    int v0 = lcnt[idx], v1 = lcnt[idx + 1];
    int s = v0 + v1;
    sums[t] = s;
    __syncthreads();
    for (int off = 1; off < 256; off <<= 1) {
        int x = (t >= off) ? sums[t - off] : 0;
        __syncthreads();
        sums[t] += x;
        __syncthreads();
    }
    int run = sums[t] - s;
    int node = node0 + idx;
    lcur[idx] = base + run;
    if (node < N) { rowptr[node] = base + run; dis[node] = rsqrtf((float)(v0 + 1)); }
    run += v0;
    lcur[idx + 1] = base + run;
    if (node + 1 < N) { rowptr[node + 1] = base + run; dis[node + 1] = rsqrtf((float)(v1 + 1)); }
    if (b == nb - 1 && t == 0) rowptr[N] = base + n;
    __syncthreads();
    for (int i = t * 4; i < n; i += 1024) {
        if (i + 3 < n) {
            int4 e = *(const int4*)(seg + i);
            int p0 = atomicAdd(&lcur[e.x & (BNODES - 1)], 1); ssrc[p0] = e.x >> RSHIFT;
            int p1 = atomicAdd(&lcur[e.y & (BNODES - 1)], 1); ssrc[p1] = e.y >> RSHIFT;
            int p2 = atomicAdd(&lcur[e.z & (BNODES - 1)], 1); ssrc[p2] = e.z >> RSHIFT;
            int p3 = atomicAdd(&lcur[e.w & (BNODES - 1)], 1); ssrc[p3] = e.w >> RSHIFT;
        } else {
            for (int j = 0; j < 4 && i + j < n; ++j) {
                int e = seg[i + j];
                int p = atomicAdd(&lcur[e & (BNODES - 1)], 1); ssrc[p] = e >> RSHIFT;
            }
        }
    }
}

// stage W^T as bf16 into LDS: wt[n][k] = bf16(W[k][n]) (validated R10)
__device__ __forceinline__ void stage_wt(const float* __restrict__ W,
                                         ushort_t* __restrict__ wt, int t) {
    const float4* W4 = (const float4*)W;
    for (int i = t; i < 1024; i += 256) {
        float4 w4 = W4[i];
        int k = i >> 4, n0 = (i & 15) * 4;
        wt[(n0 + 0) * FH + k] = rnd_bf16(w4.x);
        wt[(n0 + 1) * FH + k] = rnd_bf16(w4.y);
        wt[(n0 + 2) * FH + k] = rnd_bf16(w4.z);
        wt[(n0 + 3) * FH + k] = rnd_bf16(w4.w);
    }
}

// ---------------- layer-0 GEMM via MFMA: G = bf16((x@W)*dis) -------------
// A = x cast to bf16 in-register (no LDS A staging); B = wt (bf16 W^T LDS).
// Wave: 16 rows x 64 cols, 8 MFMA. R9 lesson: VALU gemm was LDS-bound
// (256 ds_read_b128 of W per wave); MFMA path needs ~10 LDS reads.
__global__ __launch_bounds__(256) void k_gemm0(const float* __restrict__ x,
                                               const float* __restrict__ W,
                                               const float* __restrict__ dis,
                                               ushort_t* __restrict__ G, int N) {
    __shared__ ushort_t wt[64 * FH];
    int t = threadIdx.x;
    stage_wt(W, wt, t);
    __syncthreads();
    int wv = t >> 6, lane = t & 63;
    int m = lane & 15, quad = lane >> 4;
    int row = blockIdx.x * 64 + wv * 16 + m;
    long rowc = (row < N) ? row : (N - 1);
    // A frags: A[m][k], k = quad*8+j (a0) and 32+quad*8+j (a1)
    float4 f0 = *(const float4*)(x + rowc * D + quad * 8);
    float4 f1 = *(const float4*)(x + rowc * D + quad * 8 + 4);
    float4 f2 = *(const float4*)(x + rowc * D + 32 + quad * 8);
    float4 f3 = *(const float4*)(x + rowc * D + 32 + quad * 8 + 4);
    union { short8 s; uint_t u[4]; } a0, a1;
    a0.u[0] = pk_bf16(f0.x, f0.y); a0.u[1] = pk_bf16(f0.z, f0.w);
    a0.u[2] = pk_bf16(f1.x, f1.y); a0.u[3] = pk_bf16(f1.z, f1.w);
    a1.u[0] = pk_bf16(f2.x, f2.y); a1.u[1] = pk_bf16(f2.z, f2.w);
    a1.u[2] = pk_bf16(f3.x, f3.y); a1.u[3] = pk_bf16(f3.z, f3.w);
    floatx4 acc[4];
    #pragma unroll
    for (int j = 0; j < 4; ++j) {
        short8 b0 = *(short8*)&wt[(j * 16 + m) * FH + quad * 8];
        short8 b1 = *(short8*)&wt[(j * 16 + m) * FH + 32 + quad * 8];
        floatx4 z = {0.f, 0.f, 0.f, 0.f};
        acc[j] = __builtin_amdgcn_mfma_f32_16x16x32_bf16(a0.s, b0, z, 0, 0, 0);
        acc[j] = __builtin_amdgcn_mfma_f32_16x16x32_bf16(a1.s, b1, acc[j], 0, 0, 0);
    }
    int rbase = blockIdx.x * 64 + wv * 16 + quad * 4;
    #pragma unroll
    for (int r = 0; r < 4; ++r) {
        int rr = rbase + r;
        if (rr < N) {
            float sc = dis[rr];
            #pragma unroll
            for (int j = 0; j < 4; ++j)
                G[(size_t)rr * D + j * 16 + m] = rnd_bf16(acc[j][r] * sc);
        }
    }
}

// gather one node's row with a 32-lane half-wave: 4 edge slices (sub4) x
// 8 col-lanes, unroll-4 -> 4 gathers in flight per lane (R10: latency-bound
// at 2 in flight; avg 4.3 edges/slice engages the unroll).
__device__ __forceinline__ void gather_half(const ushort_t* __restrict__ G,
                                            const int* __restrict__ ssrc,
                                            int beg, int end, int sub4, int c8,
                                            int node, float a[8]) {
    #pragma unroll
    for (int j = 0; j < 8; ++j) a[j] = 0.f;
    #define ACCUM(u)                                                       \
        {                                                                  \
            a[0] += __uint_as_float(u.x << 16);                            \
            a[1] += __uint_as_float(u.x & 0xffff0000u);                    \
            a[2] += __uint_as_float(u.y << 16);                            \
            a[3] += __uint_as_float(u.y & 0xffff0000u);                    \
            a[4] += __uint_as_float(u.z << 16);                            \
            a[5] += __uint_as_float(u.z & 0xffff0000u);                    \
            a[6] += __uint_as_float(u.w << 16);                            \
            a[7] += __uint_as_float(u.w & 0xffff0000u);                    \
        }
    if (sub4 == 0) {
        uint4 u = *(const uint4*)(G + (size_t)node * D + c8);
        ACCUM(u);
    }
    int e = beg + sub4;
    for (; e + 12 < end; e += 16) {
        int s0 = ssrc[e];
        int s1 = ssrc[e + 4];
        int s2 = ssrc[e + 8];
        int s3 = ssrc[e + 12];
        uint4 u0 = *(const uint4*)(G + (size_t)s0 * D + c8);
        uint4 u1 = *(const uint4*)(G + (size_t)s1 * D + c8);
        uint4 u2 = *(const uint4*)(G + (size_t)s2 * D + c8);
        uint4 u3 = *(const uint4*)(G + (size_t)s3 * D + c8);
        ACCUM(u0); ACCUM(u1); ACCUM(u2); ACCUM(u3);
    }
    if (e + 8 < end) {
        int s0 = ssrc[e], s1 = ssrc[e + 4], s2 = ssrc[e + 8];
        uint4 u0 = *(const uint4*)(G + (size_t)s0 * D + c8);
        uint4 u1 = *(const uint4*)(G + (size_t)s1 * D + c8);
        uint4 u2 = *(const uint4*)(G + (size_t)s2 * D + c8);
        ACCUM(u0); ACCUM(u1); ACCUM(u2);
    } else if (e + 4 < end) {
        int s0 = ssrc[e], s1 = ssrc[e + 4];
        uint4 u0 = *(const uint4*)(G + (size_t)s0 * D + c8);
        uint4 u1 = *(const uint4*)(G + (size_t)s1 * D + c8);
        ACCUM(u0); ACCUM(u1);
    } else if (e < end) {
        int s0 = ssrc[e];
        uint4 u0 = *(const uint4*)(G + (size_t)s0 * D + c8);
        ACCUM(u0);
    }
    #undef ACCUM
    // reduce 4 slices (stays within the 32-lane half: xor 8, xor 16)
    #pragma unroll
    for (int j = 0; j < 8; ++j) {
        a[j] += __shfl_xor(a[j], 8, 64);
        a[j] += __shfl_xor(a[j], 16, 64);
    }
}

// ---------------- fused agg + next-layer MFMA gemm -----------------------
// Block = 64 nodes. Phase 1: 4 waves, 2 nodes per wave concurrently (halves),
// 8 iterations; h rows -> bf16 LDS (stride FH). Phase 2: 8 MFMA per wave.
__global__ __launch_bounds__(256) void k_fagg(const ushort_t* __restrict__ G,
                                              const float* __restrict__ dis,
                                              const int* __restrict__ rowptr,
                                              const int* __restrict__ ssrc,
                                              const float* __restrict__ bias,
                                              const float* __restrict__ W,
                                              ushort_t* __restrict__ Gout,
                                              int N) {
    __shared__ ushort_t hbuf[64 * FH];
    __shared__ ushort_t wt[64 * FH];
    int t = threadIdx.x;
    stage_wt(W, wt, t);
    int wv = t >> 6, lane = t & 63;
    int half = lane >> 5;
    int sub4 = (lane >> 3) & 3;
    int c8 = (lane & 7) * 8;
    int gbase = blockIdx.x * 64;
    float4 bv0 = *(const float4*)(bias + c8);
    float4 bv1 = *(const float4*)(bias + c8 + 4);
    // phase 1: 8 iterations x 2 nodes per wave
    for (int ii = 0; ii < 8; ++ii) {
        int node = gbase + wv * 16 + ii * 2 + half;
        if (node < N) {
            int beg = rowptr[node], end = rowptr[node + 1];
            float di = dis[node];
            float a[8];
            gather_half(G, ssrc, beg, end, sub4, c8, node, a);
            if (sub4 == 0) {
                uint4 p;
                p.x = pk_bf16(a[0] * di + bv0.x, a[1] * di + bv0.y);
                p.y = pk_bf16(a[2] * di + bv0.z, a[3] * di + bv0.w);
                p.z = pk_bf16(a[4] * di + bv1.x, a[5] * di + bv1.y);
                p.w = pk_bf16(a[6] * di + bv1.z, a[7] * di + bv1.w);
                *(uint4*)&hbuf[(wv * 16 + ii * 2 + half) * FH + c8] = p;
            }
        }
    }
    __syncthreads();
    // phase 2: MFMA (layout validated R10)
    int m = lane & 15, quad = lane >> 4;
    short8 a0 = *(short8*)&hbuf[(wv * 16 + m) * FH + quad * 8];
    short8 a1 = *(short8*)&hbuf[(wv * 16 + m) * FH + 32 + quad * 8];
    floatx4 acc[4];
    #pragma unroll
    for (int j = 0; j < 4; ++j) {
        short8 b0 = *(short8*)&wt[(j * 16 + m) * FH + quad * 8];
        short8 b1 = *(short8*)&wt[(j * 16 + m) * FH + 32 + quad * 8];
        floatx4 z = {0.f, 0.f, 0.f, 0.f};
        acc[j] = __builtin_amdgcn_mfma_f32_16x16x32_bf16(a0, b0, z, 0, 0, 0);
        acc[j] = __builtin_amdgcn_mfma_f32_16x16x32_bf16(a1, b1, acc[j], 0, 0, 0);
    }
    int rbase = gbase + wv * 16 + quad * 4;
    #pragma unroll
    for (int r = 0; r < 4; ++r) {
        int row = rbase + r;
        if (row < N) {
            float sc = dis[row];
            #pragma unroll
            for (int j = 0; j < 4; ++j)
                Gout[(size_t)row * D + j * 16 + m] = rnd_bf16(acc[j][r] * sc);
        }
    }
}

// ---------------- final aggregation: out = di*(sum g) + b (fp32) ---------
// 2 nodes per wave (halves), 8 nodes per block.
__global__ __launch_bounds__(256) void k_agg(const ushort_t* __restrict__ G,
                                             const float* __restrict__ dis,
                                             const int* __restrict__ rowptr,
                                             const int* __restrict__ ssrc,
                                             const float* __restrict__ bias,
                                             float* __restrict__ out, int N) {
    int t = threadIdx.x;
    int wv = t >> 6, lane = t & 63;
    int half = lane >> 5;
    int sub4 = (lane >> 3) & 3;
    int c8 = (lane & 7) * 8;
    int node = blockIdx.x * 8 + wv * 2 + half;
    if (node >= N) return;
    int beg = rowptr[node], end = rowptr[node + 1];
    float di = dis[node];
    float a[8];
    gather_half(G, ssrc, beg, end, sub4, c8, node, a);
    if (sub4 == 0) {
        float4 bv0 = *(const float4*)(bias + c8);
        float4 bv1 = *(const float4*)(bias + c8 + 4);
        float4 r0, r1;
        r0.x = a[0] * di + bv0.x; r0.y = a[1] * di + bv0.y;
        r0.z = a[2] * di + bv0.z; r0.w = a[3] * di + bv0.w;
        r1.x = a[4] * di + bv1.x; r1.y = a[5] * di + bv1.y;
        r1.z = a[6] * di + bv1.z; r1.w = a[7] * di + bv1.w;
        float4* op = (float4*)(out + (size_t)node * D + c8);
        op[0] = r0;
        op[1] = r1;
    }
}

// ---------------- launch ----------------

extern "C" void kernel_launch(void* const* d_in, const int* in_sizes, int n_in,
                              void* d_out, int out_size, void* d_ws, size_t ws_size,
                              hipStream_t stream) {
    const float* x  = (const float*)d_in[0];
    const int*   ei = (const int*)d_in[1];
    const float* W0 = (const float*)d_in[2];
    const float* b0 = (const float*)d_in[3];
    const float* W1 = (const float*)d_in[4];
    const float* b1 = (const float*)d_in[5];
    const float* W2 = (const float*)d_in[6];
    const float* b2 = (const float*)d_in[7];
    float* out = (float*)d_out;

    const int N = in_sizes[0] / D;
    const int E = in_sizes[1] / 2;
    const int* e_src = ei;
    const int* e_dst = ei + E;

    // workspace layout
    ushort_t* B0   = (ushort_t*)d_ws;                          // N*D bf16 = 12.8 MB
    ushort_t* B1   = B0 + (size_t)N * D;                       // N*D bf16 = 12.8 MB
    float* dis     = (float*)(B1 + (size_t)N * D);             // N
    int*   rowptr  = (int*)(dis + N);                          // N+1
    int*   ssrc    = rowptr + (N + 1);                         // E
    int*   bcur    = ssrc + E;                                 // MAXB
    int*   ebuf    = (int*)d_ws;    // nb*BCAP int = 8 MB, aliases B0 head
                                    // (dead before k_gemm0 writes B0)

    const int nb = (N + BNODES - 1) >> RSHIFT;   // 196
    const int gG64 = (N + 63) / 64;              // 1563
    const int gAgg = (N + 7) / 8;                // 12500

    hipMemsetAsync(bcur, 0, MAXB * sizeof(int), stream);
    k_bucket<<<(E + 2047) / 2048, 256, 0, stream>>>(e_src, e_dst, bcur, ebuf, E, nb);
    k_csr<<<nb, 256, 0, stream>>>(ebuf, bcur, rowptr, ssrc, dis, N, nb);

    // layer 0 gemm (MFMA, bf16 x in-register): x -> B0
    k_gemm0<<<gG64, 256, 0, stream>>>(x, W0, dis, B0, N);
    // fused agg(l0) + gemm(l1): B0 -> B1
    k_fagg<<<gG64, 256, 0, stream>>>(B0, dis, rowptr, ssrc, b0, W1, B1, N);
    // fused agg(l1) + gemm(l2): B1 -> B0
    k_fagg<<<gG64, 256, 0, stream>>>(B1, dis, rowptr, ssrc, b1, W2, B0, N);
    // final agg(l2): B0 -> out (fp32)
    k_agg<<<gAgg, 256, 0, stream>>>(B0, dis, rowptr, ssrc, b2, out, N);
}